// Round 4
// baseline (117.272 us; speedup 1.0000x reference)
//
#include <hip/hip_runtime.h>
#include <math.h>

#define BLOCK 256
#define GRID  2048   // 2048 blocks x 4 waves = 8192 waves = 32/CU on 256 CUs (exact fill)

// err contribution (positive softplus; final sign folded into scale):
//   lab==1: s-lse = -softplus(a-s);  lab==2: a-lse = -softplus(s-a)
// output = -mean(err) = mean(softplus(d) over lab in {1,2}) / B
__device__ __forceinline__ float sp_term(float s, float a, int lab) {
    float d  = (lab == 1) ? (a - s) : (s - a);
    float ad = fabsf(d);
    float t  = __expf(-ad);                       // v_mul(log2e) + v_exp
    float sp = fmaxf(d, 0.0f) + __logf(1.0f + t); // stable softplus
    return (lab != 0) ? sp : 0.0f;                // lab in {0,1,2}
}

__device__ __forceinline__ float sp4(float4 s, float4 a, int4 l) {
    return sp_term(s.x, a.x, l.x) + sp_term(s.y, a.y, l.y)
         + sp_term(s.z, a.z, l.z) + sp_term(s.w, a.w, l.w);
}

// ROUND-4 CHANGE: full distance-3 prefetch. Budget decomposition puts main at
// ~31us vs a ~16us compulsory-traffic floor (96 MiB @ 6.3 TB/s); the d_ws
// poison fill (41us, harness-side) and ~38us of restore/gap overhead are not
// controllable. Theory: with only 4 load-groups/thread, distance-1 pipelining
// still leaves each wave's lifetime dominated by serialized HBM round-trips +
// ramp/drain tail (round-0 standalone evidence: 1 TB/s, VALU 11%, Occ ~45%).
// Fix: issue ALL 12 dwordx4 loads before any compute (48 data VGPRs, ~80
// total -> 6 waves/SIMD, still far above streaming needs). Per-CU, the whole
// 384 KB input share is requested within the first few us; M -> max(BW, issue).
// If dur_us does NOT move, main is pinned by harness BW-sharing/serialization
// and the session is at its structural floor (-> ROOFLINE next round).
template <bool USE_ATOMIC>
__global__ __launch_bounds__(BLOCK) void Loss_Labels_34213709479939_kernel(
        const float* __restrict__ syn,
        const float* __restrict__ ant,
        const int*   __restrict__ lab,
        float* __restrict__ dst,      // USE_ATOMIC: out scalar; else: partials[GRID]
        int n_vec,                    // number of float4 groups (B/4)
        float scale)                  // +1/B (sign already folded)
{
    const float4* __restrict__ s4 = (const float4*)syn;
    const float4* __restrict__ a4 = (const float4*)ant;
    const int4*   __restrict__ l4 = (const int4*)lab;

    const int idx    = blockIdx.x * BLOCK + threadIdx.x;
    const int stride = GRID * BLOCK;
    float acc = 0.0f;

    if (n_vec == 4 * stride) {
        // static fast path, B = 2^23: all 12 vector loads issued back-to-back
        // before any dependent compute (distance-3 prefetch, no partial waits).
        float4 s0 = s4[idx];
        float4 a0 = a4[idx];
        int4   l0 = l4[idx];
        float4 s1 = s4[idx +     stride];
        float4 a1 = a4[idx +     stride];
        int4   l1 = l4[idx +     stride];
        float4 s2 = s4[idx + 2 * stride];
        float4 a2 = a4[idx + 2 * stride];
        int4   l2 = l4[idx + 2 * stride];
        float4 s3 = s4[idx + 3 * stride];
        float4 a3 = a4[idx + 3 * stride];
        int4   l3 = l4[idx + 3 * stride];
        acc = (sp4(s0, a0, l0) + sp4(s1, a1, l1))
            + (sp4(s2, a2, l2) + sp4(s3, a3, l3));
    } else {
        // generic path (any B divisible by 4)
        const int iters = n_vec / stride;
        for (int k = 0; k < iters; ++k) {
            int i = idx + k * stride;
            acc += sp4(s4[i], a4[i], l4[i]);
        }
        int i = iters * stride + idx;
        if (i < n_vec)
            acc += sp4(s4[i], a4[i], l4[i]);
    }

    // wave-64 down-reduction
    #pragma unroll
    for (int off = 32; off > 0; off >>= 1)
        acc += __shfl_down(acc, off, 64);

    __shared__ float smem[BLOCK / 64];
    int lane = threadIdx.x & 63;
    int wid  = threadIdx.x >> 6;
    if (lane == 0) smem[wid] = acc;
    __syncthreads();

    if (threadIdx.x == 0) {
        float t = smem[0] + smem[1] + smem[2] + smem[3];
        if (USE_ATOMIC) {
            atomicAdd(dst, t * scale);           // legacy contended path
        } else {
            dst[blockIdx.x] = t;                 // disjoint address, no contention
        }
    }
}

// Second dispatch: sum GRID=2048 partials (8 KiB, L2/L3-hot) and overwrite out
// (also erases the 0xAA poison). One wave, float4 loads, no smem, no barrier.
__global__ __launch_bounds__(64) void Loss_Labels_34213709479939_reduce(
        const float* __restrict__ partials,
        float* __restrict__ out,
        float scale)
{
    const float4* __restrict__ p4 = (const float4*)partials;  // 512 float4
    float acc = 0.0f;
    #pragma unroll
    for (int i = 0; i < (GRID / 4) / 64; ++i) {               // 8 per lane
        float4 v = p4[threadIdx.x + 64 * i];
        acc += (v.x + v.y) + (v.z + v.w);
    }
    #pragma unroll
    for (int off = 32; off > 0; off >>= 1)
        acc += __shfl_down(acc, off, 64);
    if (threadIdx.x == 0)
        out[0] = acc * scale;                                 // plain store
}

extern "C" void kernel_launch(void* const* d_in, const int* in_sizes, int n_in,
                              void* d_out, int out_size, void* d_ws, size_t ws_size,
                              hipStream_t stream) {
    const float* syn = (const float*)d_in[0];
    const float* ant = (const float*)d_in[1];
    const int*   lab = (const int*)d_in[2];
    float*       out = (float*)d_out;

    const int B     = in_sizes[0];       // (B,1) flat = B elements
    const int n_vec = B / 4;             // B = 2^23, divisible by 4
    const float scale = 1.0f / (float)B; // -mean(err) == +mean(softplus)

    if (ws_size >= GRID * sizeof(float)) {
        float* partials = (float*)d_ws;
        Loss_Labels_34213709479939_kernel<false><<<GRID, BLOCK, 0, stream>>>(
            syn, ant, lab, partials, n_vec, scale);
        Loss_Labels_34213709479939_reduce<<<1, 64, 0, stream>>>(
            partials, out, scale);
    } else {
        // fallback: contended-atomic single dispatch (original behavior)
        Loss_Labels_34213709479939_kernel<true><<<GRID, BLOCK, 0, stream>>>(
            syn, ant, lab, out, n_vec, scale);
    }
}

// Round 5
// 115.802 us; speedup vs baseline: 1.0127x; 1.0127x over previous
//
#include <hip/hip_runtime.h>
#include <math.h>

#define BLOCK 256
#define GRID  2048   // 2048 blocks x 4 waves = 8192 waves = 32/CU on 256 CUs (exact fill)

// err contribution (positive softplus; final sign folded into scale):
//   lab==1: s-lse = -softplus(a-s);  lab==2: a-lse = -softplus(s-a)
// output = -mean(err) = mean(softplus(d) over lab in {1,2}) / B
__device__ __forceinline__ float sp_term(float s, float a, int lab) {
    float d  = (lab == 1) ? (a - s) : (s - a);
    float ad = fabsf(d);
    float t  = __expf(-ad);                       // v_mul(log2e) + v_exp
    float sp = fmaxf(d, 0.0f) + __logf(1.0f + t); // stable softplus
    return (lab != 0) ? sp : 0.0f;                // lab in {0,1,2}
}

__device__ __forceinline__ float sp4(float4 s, float4 a, int4 l) {
    return sp_term(s.x, a.x, l.x) + sp_term(s.y, a.y, l.y)
         + sp_term(s.z, a.z, l.z) + sp_term(s.w, a.w, l.w);
}

// ROUND-5 CHANGE: distance-2 pipeline at FULL occupancy. Round-4 post-mortem:
// holding all 12 loads (48 data VGPRs) crossed the 64-VGPR cliff -> 16 waves/CU
// (halved TLP), main ~31 -> ~35us. Occupancy-sensitivity at constant traffic
// means main is latency-bound (TLP x MLP product), not BW-pinned. The untested
// corner is d2 @ 32 waves/CU: two groups in flight ahead of compute (~36 live
// data VGPRs, ~55 total <= 64), enforced via __launch_bounds__(256, 8)
// (2nd arg = min waves per EU -> compiler caps VGPR at 64). Loads are
// hand-interleaved with compute so the natural schedule fits without spills.
// Pre-committed: if this lands ~114-115 (pure revert), main is at the harness
// floor (41us d_ws poison-fill + ~38us restore/gaps + ~16us compulsory reads)
// and the session declares ROOFLINE.
template <bool USE_ATOMIC>
__global__ __launch_bounds__(BLOCK, 8) void Loss_Labels_34213709479939_kernel(
        const float* __restrict__ syn,
        const float* __restrict__ ant,
        const int*   __restrict__ lab,
        float* __restrict__ dst,      // USE_ATOMIC: out scalar; else: partials[GRID]
        int n_vec,                    // number of float4 groups (B/4)
        float scale)                  // +1/B (sign already folded)
{
    const float4* __restrict__ s4 = (const float4*)syn;
    const float4* __restrict__ a4 = (const float4*)ant;
    const int4*   __restrict__ l4 = (const int4*)lab;

    const int idx    = blockIdx.x * BLOCK + threadIdx.x;
    const int stride = GRID * BLOCK;
    float acc = 0.0f;

    if (n_vec == 4 * stride) {
        // static fast path, B = 2^23: distance-2 software pipeline.
        // In flight while computing group k: groups k+1 and k+2 (24 data VGPRs)
        // plus the dying group k (12) -> ~36 live data regs, fits 64-VGPR cap.
        float4 s0 = s4[idx];
        float4 a0 = a4[idx];
        int4   l0 = l4[idx];
        float4 s1 = s4[idx + stride];
        float4 a1 = a4[idx + stride];
        int4   l1 = l4[idx + stride];

        float4 s2 = s4[idx + 2 * stride];
        float4 a2 = a4[idx + 2 * stride];
        int4   l2 = l4[idx + 2 * stride];
        acc += sp4(s0, a0, l0);       // g1, g2 in flight during this chain

        float4 s3 = s4[idx + 3 * stride];
        float4 a3 = a4[idx + 3 * stride];
        int4   l3 = l4[idx + 3 * stride];
        acc += sp4(s1, a1, l1);       // g2, g3 in flight during this chain

        acc += sp4(s2, a2, l2);
        acc += sp4(s3, a3, l3);
    } else {
        // generic path (any B divisible by 4)
        const int iters = n_vec / stride;
        for (int k = 0; k < iters; ++k) {
            int i = idx + k * stride;
            acc += sp4(s4[i], a4[i], l4[i]);
        }
        int i = iters * stride + idx;
        if (i < n_vec)
            acc += sp4(s4[i], a4[i], l4[i]);
    }

    // wave-64 down-reduction
    #pragma unroll
    for (int off = 32; off > 0; off >>= 1)
        acc += __shfl_down(acc, off, 64);

    __shared__ float smem[BLOCK / 64];
    int lane = threadIdx.x & 63;
    int wid  = threadIdx.x >> 6;
    if (lane == 0) smem[wid] = acc;
    __syncthreads();

    if (threadIdx.x == 0) {
        float t = smem[0] + smem[1] + smem[2] + smem[3];
        if (USE_ATOMIC) {
            atomicAdd(dst, t * scale);           // legacy contended path
        } else {
            dst[blockIdx.x] = t;                 // disjoint address, no contention
        }
    }
}

// Second dispatch: sum GRID=2048 partials (8 KiB, L2/L3-hot) and overwrite out
// (also erases the 0xAA poison). One wave, float4 loads, no smem, no barrier.
__global__ __launch_bounds__(64) void Loss_Labels_34213709479939_reduce(
        const float* __restrict__ partials,
        float* __restrict__ out,
        float scale)
{
    const float4* __restrict__ p4 = (const float4*)partials;  // 512 float4
    float acc = 0.0f;
    #pragma unroll
    for (int i = 0; i < (GRID / 4) / 64; ++i) {               // 8 per lane
        float4 v = p4[threadIdx.x + 64 * i];
        acc += (v.x + v.y) + (v.z + v.w);
    }
    #pragma unroll
    for (int off = 32; off > 0; off >>= 1)
        acc += __shfl_down(acc, off, 64);
    if (threadIdx.x == 0)
        out[0] = acc * scale;                                 // plain store
}

extern "C" void kernel_launch(void* const* d_in, const int* in_sizes, int n_in,
                              void* d_out, int out_size, void* d_ws, size_t ws_size,
                              hipStream_t stream) {
    const float* syn = (const float*)d_in[0];
    const float* ant = (const float*)d_in[1];
    const int*   lab = (const int*)d_in[2];
    float*       out = (float*)d_out;

    const int B     = in_sizes[0];       // (B,1) flat = B elements
    const int n_vec = B / 4;             // B = 2^23, divisible by 4
    const float scale = 1.0f / (float)B; // -mean(err) == +mean(softplus)

    if (ws_size >= GRID * sizeof(float)) {
        float* partials = (float*)d_ws;
        Loss_Labels_34213709479939_kernel<false><<<GRID, BLOCK, 0, stream>>>(
            syn, ant, lab, partials, n_vec, scale);
        Loss_Labels_34213709479939_reduce<<<1, 64, 0, stream>>>(
            partials, out, scale);
    } else {
        // fallback: contended-atomic single dispatch (original behavior)
        Loss_Labels_34213709479939_kernel<true><<<GRID, BLOCK, 0, stream>>>(
            syn, ant, lab, out, n_vec, scale);
    }
}